// Round 1
// baseline (241.081 us; speedup 1.0000x reference)
//
#include <hip/hip_runtime.h>
#include <hip/hip_bf16.h>

#define B_    8
#define S_    32
#define H_    2048
#define NH_   16
#define NKV_  2
#define HD_   128
#define KV_   8192
#define G_    8
#define M_    256      /* B*S */
#define NQKV  2560     /* fused proj N: 2048 q | 256 k | 256 v */
#define SCALE_ 0.08838834764831845f

typedef __bf16 bf16x8 __attribute__((ext_vector_type(8)));
typedef float  f32x4  __attribute__((ext_vector_type(4)));

__device__ __forceinline__ unsigned short f2b(float f){
  unsigned u = __float_as_uint(f);
  u = u + 0x7FFFu + ((u>>16)&1u);           // RNE f32->bf16
  return (unsigned short)(u>>16);
}
__device__ __forceinline__ float b2f(unsigned short h){
  return __uint_as_float(((unsigned)h)<<16);
}
__device__ __forceinline__ bf16x8 ld_frag(const unsigned short* p){
  union { uint4 u; bf16x8 b; } cv;
  cv.u = *(const uint4*)p;
  return cv.b;
}
__device__ __forceinline__ f32x4 mf(bf16x8 a, bf16x8 b, f32x4 c){
  return __builtin_amdgcn_mfma_f32_16x16x32_bf16(a, b, c, 0, 0, 0);
}

// ---------------- K0: hidden_states f32 -> bf16 ----------------
__global__ __launch_bounds__(256) void k_cvt(const float* __restrict__ x,
                                             unsigned short* __restrict__ y){
  const int i = (blockIdx.x*256 + threadIdx.x)*4;
  const float4 v = *(const float4*)(x + i);
  ushort4 o; o.x=f2b(v.x); o.y=f2b(v.y); o.z=f2b(v.z); o.w=f2b(v.w);
  *(ushort4*)(y + i) = o;
}

// ---------------- K1: fused QKV projection GEMM (bf16 MFMA) ----------------
// A: hsb [256][2048] bf16. Out: raw [256][2560] f32 (bias added).
__global__ __launch_bounds__(256) void k_gemm_qkv(
    const unsigned short* __restrict__ A,
    const float* __restrict__ qw, const float* __restrict__ kw, const float* __restrict__ vw,
    const float* __restrict__ qbv, const float* __restrict__ kbv, const float* __restrict__ vbv,
    float* __restrict__ out)
{
  __shared__ unsigned short As[64][56];   // pad 56 (112B rows: 16B-aligned, spreads banks)
  __shared__ unsigned short Bs[64][56];   // Bs[n][k] (W transposed)
  const int n0 = blockIdx.x*64, m0 = blockIdx.y*64;
  const float* W; const float* bias; int ldw, wc0;
  if(n0 < 2048)      { W=qw; bias=qbv; ldw=2048; wc0=n0; }
  else if(n0 < 2304) { W=kw; bias=kbv; ldw=256;  wc0=n0-2048; }
  else               { W=vw; bias=vbv; ldw=256;  wc0=n0-2304; }
  const int t = threadIdx.x, lane = t&63, wid = t>>6;
  const int wr = wid>>1, wc = wid&1, l15 = lane&15, lq = lane>>4;
  const int ar = t>>2,  ac = (t&3)*8;
  const int bk = t>>5,  bn = (t&31)*2;
  f32x4 acc[2][2] = {};
  for(int k0 = 0; k0 < 2048; k0 += 32){
    __syncthreads();
    *(uint4*)(&As[ar][ac]) = *(const uint4*)(A + (m0+ar)*2048 + k0 + ac);
    #pragma unroll
    for(int p=0;p<4;p++){
      const int kk = bk + p*8;
      const float2 wv = *(const float2*)(W + (long)(k0+kk)*ldw + wc0 + bn);
      Bs[bn  ][kk] = f2b(wv.x);
      Bs[bn+1][kk] = f2b(wv.y);
    }
    __syncthreads();
    const bf16x8 a0 = ld_frag(&As[wr*32      + l15][lq*8]);
    const bf16x8 a1 = ld_frag(&As[wr*32 + 16 + l15][lq*8]);
    const bf16x8 b0 = ld_frag(&Bs[wc*32      + l15][lq*8]);
    const bf16x8 b1 = ld_frag(&Bs[wc*32 + 16 + l15][lq*8]);
    acc[0][0] = mf(a0,b0,acc[0][0]);
    acc[0][1] = mf(a0,b1,acc[0][1]);
    acc[1][0] = mf(a1,b0,acc[1][0]);
    acc[1][1] = mf(a1,b1,acc[1][1]);
  }
  #pragma unroll
  for(int mi=0;mi<2;mi++)
    #pragma unroll
    for(int nj=0;nj<2;nj++){
      const int col = n0 + wc*32 + nj*16 + l15;
      const float bv = bias[wc0 + wc*32 + nj*16 + l15];
      #pragma unroll
      for(int rr=0;rr<4;rr++){
        const int row = m0 + wr*32 + mi*16 + lq*4 + rr;
        out[row*NQKV + col] = acc[mi][nj][rr] + bv;
      }
    }
}

// ---------------- K2: RoPE + pack to bf16 attention layouts ----------------
// Qb [b][kv][g*32+s][d], Kn/Vn [b][kv][s][d]
__global__ __launch_bounds__(128) void k_rope(
    const float* __restrict__ raw, const float* __restrict__ cosb, const float* __restrict__ sinb,
    unsigned short* __restrict__ Qb, unsigned short* __restrict__ Kn, unsigned short* __restrict__ Vn)
{
  const int r = blockIdx.x, hh = blockIdx.y, d = threadIdx.x;
  const int b = r>>5, s = r&31;
  const float cv = cosb[(b*S_+s)*HD_ + d];
  const float sv = sinb[(b*S_+s)*HD_ + d];
  const int dp = (d<64)? d+64 : d-64;
  if(hh < 16){
    const float x  = raw[r*NQKV + hh*HD_ + d];
    const float xo = raw[r*NQKV + hh*HD_ + dp];
    const float y  = x*cv + ((d<64)? -xo : xo)*sv;
    const int kvh = hh>>3, g = hh&7;
    Qb[((long)(b*NKV_+kvh)*M_ + g*S_ + s)*HD_ + d] = f2b(y);
  } else if(hh < 18){
    const int kvh = hh-16;
    const float x  = raw[r*NQKV + 2048 + kvh*HD_ + d];
    const float xo = raw[r*NQKV + 2048 + kvh*HD_ + dp];
    const float y  = x*cv + ((d<64)? -xo : xo)*sv;
    Kn[((long)(b*NKV_+kvh)*S_ + s)*HD_ + d] = f2b(y);
  } else {
    const int kvh = hh-18;
    Vn[((long)(b*NKV_+kvh)*S_ + s)*HD_ + d] = f2b(raw[r*NQKV + 2304 + kvh*HD_ + d]);
  }
}

// ---------------- K3: split-KV attention ----------------
// grid (chunk=64, kv=2, b=8), 512 threads = 8 waves; each block: 256 q rows x 128 kv.
__global__ __launch_bounds__(512) void k_attn(
    const unsigned short* __restrict__ Qb,
    const unsigned short* __restrict__ Kn,
    const unsigned short* __restrict__ Vn,
    const float* __restrict__ kc, const float* __restrict__ vc,
    const float* __restrict__ mask, const int* __restrict__ rpp,
    unsigned short* __restrict__ num, float* __restrict__ mbuf, float* __restrict__ lbuf)
{
  __shared__ unsigned short Ks[128][136];      // [kv][hd]
  __shared__ unsigned short Vt[128][136];      // [hd][kv] (transposed)
  __shared__ unsigned short Ps[8][16][136];    // per-wave P tile [q][kv]
  const int ck = blockIdx.x, kvh = blockIdx.y, b = blockIdx.z;
  const int bk = b*NKV_ + kvh;
  const int rp = *rpp;
  const int t = threadIdx.x;
  // ---- stage K (row-major) and V (transposed); replace-window rows from Kn/Vn ----
  {
    const int row = t>>2, c0 = (t&3)*32;
    const int kvg = ck*128 + row;
    const int off = kvg - rp;
    if(off >= 0 && off < S_){
      const unsigned short* sk = Kn + ((long)bk*S_ + off)*HD_ + c0;
      #pragma unroll
      for(int i=0;i<4;i++)
        *(uint4*)(&Ks[row][c0 + i*8]) = *(const uint4*)(sk + i*8);
      const unsigned short* sv = Vn + ((long)bk*S_ + off)*HD_ + c0;
      #pragma unroll
      for(int i=0;i<32;i++)
        Vt[c0 + i][row] = sv[i];
    } else {
      const float* skf = kc + ((long)bk*KV_ + kvg)*HD_ + c0;
      #pragma unroll
      for(int i=0;i<8;i++){
        const float4 v = *(const float4*)(skf + i*4);
        ushort4 o; o.x=f2b(v.x); o.y=f2b(v.y); o.z=f2b(v.z); o.w=f2b(v.w);
        *(ushort4*)(&Ks[row][c0 + i*4]) = o;
      }
      const float* svf = vc + ((long)bk*KV_ + kvg)*HD_ + c0;
      #pragma unroll
      for(int i=0;i<8;i++){
        const float4 v = *(const float4*)(svf + i*4);
        Vt[c0+i*4+0][row] = f2b(v.x);
        Vt[c0+i*4+1][row] = f2b(v.y);
        Vt[c0+i*4+2][row] = f2b(v.z);
        Vt[c0+i*4+3][row] = f2b(v.w);
      }
    }
  }
  __syncthreads();
  const int lane = t&63, wid = t>>6, l15 = lane&15, lq = lane>>4;
  const unsigned short* Qbb = Qb + (long)bk*M_*HD_;
  for(int qt = 0; qt < 2; qt++){
    const int q0 = wid*32 + qt*16;
    // ---- scores: D[q][kv] = Q x K^T ----
    f32x4 sc[8] = {};
    #pragma unroll
    for(int ks=0; ks<4; ks++){
      const bf16x8 a = ld_frag(Qbb + (q0 + l15)*HD_ + ks*32 + lq*8);
      #pragma unroll
      for(int kt=0; kt<8; kt++){
        const bf16x8 bb = ld_frag(&Ks[kt*16 + l15][ks*32 + lq*8]);
        sc[kt] = mf(a, bb, sc[kt]);
      }
    }
    // ---- chunk-local softmax (rows split over lq,reg; butterfly over l15) ----
    float pm[4], pl[4];
    float pv[8][4];
    #pragma unroll
    for(int r=0;r<4;r++){
      const int s_idx = (q0 + lq*4 + r) & 31;
      const float* mrow = mask + ((long)b*S_ + s_idx)*KV_ + ck*128;
      float mx = -3.0e38f;
      #pragma unroll
      for(int kt=0;kt<8;kt++){
        const float x = sc[kt][r]*SCALE_ + mrow[kt*16 + l15];
        pv[kt][r] = x;
        mx = fmaxf(mx, x);
      }
      #pragma unroll
      for(int dd=1; dd<16; dd<<=1) mx = fmaxf(mx, __shfl_xor(mx, dd, 64));
      float sm = 0.f;
      #pragma unroll
      for(int kt=0;kt<8;kt++){
        const float e = __expf(pv[kt][r]-mx);
        pv[kt][r] = e; sm += e;
      }
      #pragma unroll
      for(int dd=1; dd<16; dd<<=1) sm += __shfl_xor(sm, dd, 64);
      pm[r]=mx; pl[r]=sm;
    }
    if(l15 == 0){
      #pragma unroll
      for(int r=0;r<4;r++){
        mbuf[((long)bk*64 + ck)*M_ + q0 + lq*4 + r] = pm[r];
        lbuf[((long)bk*64 + ck)*M_ + q0 + lq*4 + r] = pl[r];
      }
    }
    // ---- P -> LDS (D-layout scatter, bf16) ----
    #pragma unroll
    for(int kt=0;kt<8;kt++)
      #pragma unroll
      for(int r=0;r<4;r++)
        Ps[wid][lq*4+r][kt*16+l15] = f2b(pv[kt][r]);
    // ---- PV: D[q][hd] = P x V ----
    f32x4 oc[8] = {};
    #pragma unroll
    for(int ks=0; ks<4; ks++){
      const bf16x8 a = ld_frag(&Ps[wid][l15][ks*32 + lq*8]);
      #pragma unroll
      for(int ht=0; ht<8; ht++){
        const bf16x8 bb = ld_frag(&Vt[ht*16 + l15][ks*32 + lq*8]);
        oc[ht] = mf(a, bb, oc[ht]);
      }
    }
    unsigned short* np_ = num + (((long)bk*64 + ck)*M_ + q0)*HD_;
    #pragma unroll
    for(int ht=0; ht<8; ht++)
      #pragma unroll
      for(int r=0;r<4;r++)
        np_[(lq*4+r)*HD_ + ht*16 + l15] = f2b(oc[ht][r]);
  }
}

// ---------------- K4: combine split-KV partials ----------------
__global__ __launch_bounds__(128) void k_comb(
    const unsigned short* __restrict__ num, const float* __restrict__ mbuf,
    const float* __restrict__ lbuf, unsigned short* __restrict__ attnb)
{
  const int q = blockIdx.x, kvh = blockIdx.y, b = blockIdx.z, d = threadIdx.x;
  const int bk = b*NKV_ + kvh;
  float M = -3.0e38f;
  for(int c=0;c<64;c++) M = fmaxf(M, mbuf[((long)bk*64 + c)*M_ + q]);
  float den = 0.f, acc = 0.f;
  for(int c=0;c<64;c++){
    const long ix = ((long)bk*64 + c)*M_ + q;
    const float w = __expf(mbuf[ix] - M);
    den += lbuf[ix]*w;
    acc += w * b2f(num[ix*HD_ + d]);
  }
  const int g = q>>5, s = q&31, h = kvh*G_ + g;
  attnb[((long)(b*S_+s))*2048 + h*HD_ + d] = f2b(acc/den);
}

// ---------------- K5: output projection GEMM ----------------
__global__ __launch_bounds__(256) void k_gemm_o(
    const unsigned short* __restrict__ A,     // attnb [256][2048] bf16
    const float* __restrict__ W,              // o_w [2048][2048] f32
    float* __restrict__ out)                  // d_out [256][2048] f32
{
  __shared__ unsigned short As[64][56];
  __shared__ unsigned short Bs[64][56];
  const int n0 = blockIdx.x*64, m0 = blockIdx.y*64;
  const int t = threadIdx.x, lane = t&63, wid = t>>6;
  const int wr = wid>>1, wc = wid&1, l15 = lane&15, lq = lane>>4;
  const int ar = t>>2,  ac = (t&3)*8;
  const int bk = t>>5,  bn = (t&31)*2;
  f32x4 acc[2][2] = {};
  for(int k0 = 0; k0 < 2048; k0 += 32){
    __syncthreads();
    *(uint4*)(&As[ar][ac]) = *(const uint4*)(A + (m0+ar)*2048 + k0 + ac);
    #pragma unroll
    for(int p=0;p<4;p++){
      const int kk = bk + p*8;
      const float2 wv = *(const float2*)(W + (long)(k0+kk)*2048 + n0 + bn);
      Bs[bn  ][kk] = f2b(wv.x);
      Bs[bn+1][kk] = f2b(wv.y);
    }
    __syncthreads();
    const bf16x8 a0 = ld_frag(&As[wr*32      + l15][lq*8]);
    const bf16x8 a1 = ld_frag(&As[wr*32 + 16 + l15][lq*8]);
    const bf16x8 b0 = ld_frag(&Bs[wc*32      + l15][lq*8]);
    const bf16x8 b1 = ld_frag(&Bs[wc*32 + 16 + l15][lq*8]);
    acc[0][0] = mf(a0,b0,acc[0][0]);
    acc[0][1] = mf(a0,b1,acc[0][1]);
    acc[1][0] = mf(a1,b0,acc[1][0]);
    acc[1][1] = mf(a1,b1,acc[1][1]);
  }
  #pragma unroll
  for(int mi=0;mi<2;mi++)
    #pragma unroll
    for(int nj=0;nj<2;nj++){
      const int col = n0 + wc*32 + nj*16 + l15;
      #pragma unroll
      for(int rr=0;rr<4;rr++){
        const int row = m0 + wr*32 + mi*16 + lq*4 + rr;
        out[row*2048 + col] = acc[mi][nj][rr];
      }
    }
}

extern "C" void kernel_launch(void* const* d_in, const int* in_sizes, int n_in,
                              void* d_out, int out_size, void* d_ws, size_t ws_size,
                              hipStream_t stream){
  (void)in_sizes; (void)n_in; (void)out_size; (void)ws_size;
  const float* hs   = (const float*)d_in[0];
  const float* cosb = (const float*)d_in[1];
  const float* sinb = (const float*)d_in[2];
  const float* kc   = (const float*)d_in[3];
  const float* vc   = (const float*)d_in[4];
  const float* mask = (const float*)d_in[5];
  const int*   rp   = (const int*)  d_in[6];
  const float* qw   = (const float*)d_in[7];
  const float* qb   = (const float*)d_in[8];
  const float* kw   = (const float*)d_in[9];
  const float* kb   = (const float*)d_in[10];
  const float* vw   = (const float*)d_in[11];
  const float* vb   = (const float*)d_in[12];
  const float* ow   = (const float*)d_in[13];
  char* ws = (char*)d_ws;
  // ws layout (bytes)
  unsigned short* hsb   = (unsigned short*)(ws + 0);          // 1,048,576
  float*          raw   = (float*)         (ws + 1048576);    // 2,621,440
  unsigned short* Qb    = (unsigned short*)(ws + 3670016);    // 1,048,576
  unsigned short* Kn    = (unsigned short*)(ws + 4718592);    //   131,072
  unsigned short* Vn    = (unsigned short*)(ws + 4849664);    //   131,072
  unsigned short* attnb = (unsigned short*)(ws + 4980736);    // 1,048,576
  float*          mbuf  = (float*)         (ws + 6029312);    // 1,048,576
  float*          lbuf  = (float*)         (ws + 7077888);    // 1,048,576
  unsigned short* num   = (unsigned short*)(ws + 8126464);    // 67,108,864
  float* outp = (float*)d_out;

  k_cvt     <<<dim3(512),      dim3(256), 0, stream>>>(hs, hsb);
  k_gemm_qkv<<<dim3(40,4),     dim3(256), 0, stream>>>(hsb, qw,kw,vw, qb,kb,vb, raw);
  k_rope    <<<dim3(256,20),   dim3(128), 0, stream>>>(raw, cosb, sinb, Qb, Kn, Vn);
  k_attn    <<<dim3(64,2,8),   dim3(512), 0, stream>>>(Qb, Kn, Vn, kc, vc, mask, rp, num, mbuf, lbuf);
  k_comb    <<<dim3(256,2,8),  dim3(128), 0, stream>>>(num, mbuf, lbuf, attnb);
  k_gemm_o  <<<dim3(32,4),     dim3(256), 0, stream>>>(attnb, ow, outp);
}